// Round 1
// baseline (276.987 us; speedup 1.0000x reference)
//
#include <hip/hip_runtime.h>

#define DDIM 256
#define NTOK 4096   // B*S = 64*64
#define NEGN 8192
#define TM 64
#define TN 64
#define TK 32
#define LDT 40      // padded halfs per LDS row (32 + 8) -> 80B stride, 16B aligned

typedef __attribute__((ext_vector_type(8))) short bf16x8;
typedef __attribute__((ext_vector_type(4))) float f32x4;

__device__ inline unsigned short f2bf(float f) {
    unsigned int u = __float_as_uint(f);
    unsigned int r = u + 0x7FFFu + ((u >> 16) & 1u);
    return (unsigned short)(r >> 16);
}

// ---------------------------------------------------------------------------
// Kernel 1: gather + fp32->bf16 convert.
// Row space: [0,NTOK) z rows | [NTOK,NTOK+Lpe) E_en rows | next Lpf E_fr rows |
//            last NTOK be_fr rows. Each 64-lane group handles one 256-elem row.
// ---------------------------------------------------------------------------
__global__ void gather_kernel(
    const float* __restrict__ zs,
    const float* __restrict__ W_en, const float* __restrict__ W_fr,
    const int* __restrict__ pos_en, const int* __restrict__ neg_en,
    const int* __restrict__ pos_fr, const int* __restrict__ neg_fr,
    const int* __restrict__ x_fr,
    const float* __restrict__ kappa_en, const float* __restrict__ kappa_fr,
    unsigned short* __restrict__ z_bf,
    unsigned short* __restrict__ E_en, unsigned short* __restrict__ E_fr,
    unsigned short* __restrict__ be_fr,
    float* __restrict__ w_en, float* __restrict__ w_fr,
    int Pe, int Pf, int Lpe, int Lpf)
{
    int row  = blockIdx.x * 4 + (threadIdx.x >> 6);
    int lane = threadIdx.x & 63;
    const float* src = nullptr;
    unsigned short* dst = nullptr;
    bool zero = false;

    if (row < NTOK) {
        src = zs + (size_t)row * DDIM;
        dst = z_bf + (size_t)row * DDIM;
    } else if (row < NTOK + Lpe) {
        int j = row - NTOK;
        int Le = Pe + NEGN;
        int idx = 0;
        if (j < Pe)      idx = pos_en[j];
        else if (j < Le) idx = neg_en[j - Pe];
        else             zero = true;
        src = W_en + (size_t)idx * DDIM;
        dst = E_en + (size_t)j * DDIM;
        if (lane == 0) w_en[j] = (j < Pe) ? 1.0f : (j < Le ? kappa_en[0] : 0.0f);
    } else if (row < NTOK + Lpe + Lpf) {
        int j = row - NTOK - Lpe;
        int Lf = Pf + NEGN;
        int idx = 0;
        if (j < Pf)      idx = pos_fr[j];
        else if (j < Lf) idx = neg_fr[j - Pf];
        else             zero = true;
        src = W_fr + (size_t)idx * DDIM;
        dst = E_fr + (size_t)j * DDIM;
        if (lane == 0) w_fr[j] = (j < Pf) ? 1.0f : (j < Lf ? kappa_fr[0] : 0.0f);
    } else if (row < NTOK + Lpe + Lpf + NTOK) {
        int j = row - NTOK - Lpe - Lpf;
        int idx = x_fr[j];
        src = W_fr + (size_t)idx * DDIM;
        dst = be_fr + (size_t)j * DDIM;
    } else {
        return;
    }

    int d = lane * 4;
    float4 v;
    if (zero) { v.x = v.y = v.z = v.w = 0.0f; }
    else      { v = *(const float4*)(src + d); }
    ushort4 o;
    o.x = f2bf(v.x); o.y = f2bf(v.y); o.z = f2bf(v.z); o.w = f2bf(v.w);
    *(ushort4*)(dst + d) = o;
}

// ---------------------------------------------------------------------------
// Kernel 2: generic fused  out[m] += sum_n w[n] * exp( A[m,:] . B[n,:] )
// A: [M x 256] bf16 row-major, B: [N x 256] bf16 row-major (i.e. B^T input).
// Tile 64x64, 256 threads = 4 waves; wave w owns m-rows [16w,16w+16), all 64 n.
// mfma_f32_16x16x32_bf16 layouts (HW-verified per guide):
//   A/B frag: lane holds row (lane&15), 8 k at (lane>>4)*8
//   C/D:      col = lane&15, row = (lane>>4)*4 + reg
// ---------------------------------------------------------------------------
__global__ __launch_bounds__(256) void expsum_gemm(
    const unsigned short* __restrict__ A,
    const unsigned short* __restrict__ Bm,
    const float* __restrict__ wts,
    float* __restrict__ out,
    int sAbatch, int sBbatch, int wstride, int ostride)
{
    __shared__ __align__(16) unsigned short lda[TM * LDT];
    __shared__ __align__(16) unsigned short ldb[TN * LDT];

    int batch = blockIdx.z;
    const unsigned short* Ab = A  + (size_t)batch * sAbatch + (size_t)blockIdx.x * TM * DDIM;
    const unsigned short* Bb = Bm + (size_t)batch * sBbatch + (size_t)blockIdx.y * TN * DDIM;

    int t      = threadIdx.x;
    int srow   = t >> 2;        // staging: row 0..63
    int schunk = t & 3;         // staging: 8-half chunk 0..3
    int lane   = t & 63;
    int wave   = t >> 6;
    int col    = lane & 15;
    int quad   = lane >> 4;

    f32x4 acc0 = {0.f,0.f,0.f,0.f};
    f32x4 acc1 = {0.f,0.f,0.f,0.f};
    f32x4 acc2 = {0.f,0.f,0.f,0.f};
    f32x4 acc3 = {0.f,0.f,0.f,0.f};

    for (int kk = 0; kk < DDIM; kk += TK) {
        uint4 av = *(const uint4*)(Ab + (size_t)srow * DDIM + kk + schunk * 8);
        uint4 bv = *(const uint4*)(Bb + (size_t)srow * DDIM + kk + schunk * 8);
        __syncthreads();
        *(uint4*)(lda + srow * LDT + schunk * 8) = av;
        *(uint4*)(ldb + srow * LDT + schunk * 8) = bv;
        __syncthreads();

        bf16x8 af = *(const bf16x8*)(lda + (wave * 16 + col) * LDT + quad * 8);
        bf16x8 b0 = *(const bf16x8*)(ldb + ( 0 + col) * LDT + quad * 8);
        bf16x8 b1 = *(const bf16x8*)(ldb + (16 + col) * LDT + quad * 8);
        bf16x8 b2 = *(const bf16x8*)(ldb + (32 + col) * LDT + quad * 8);
        bf16x8 b3 = *(const bf16x8*)(ldb + (48 + col) * LDT + quad * 8);
        acc0 = __builtin_amdgcn_mfma_f32_16x16x32_bf16(af, b0, acc0, 0, 0, 0);
        acc1 = __builtin_amdgcn_mfma_f32_16x16x32_bf16(af, b1, acc1, 0, 0, 0);
        acc2 = __builtin_amdgcn_mfma_f32_16x16x32_bf16(af, b2, acc2, 0, 0, 0);
        acc3 = __builtin_amdgcn_mfma_f32_16x16x32_bf16(af, b3, acc3, 0, 0, 0);
    }

    // epilogue: weight * exp, reduce over the 64 n columns of this tile
    const float* wb = wts + (size_t)batch * wstride + (size_t)blockIdx.y * TN;
    float w0 = wb[ 0 + col];
    float w1 = wb[16 + col];
    float w2 = wb[32 + col];
    float w3 = wb[48 + col];

    float tot0 = w0 * expf(acc0.x) + w1 * expf(acc1.x) + w2 * expf(acc2.x) + w3 * expf(acc3.x);
    float tot1 = w0 * expf(acc0.y) + w1 * expf(acc1.y) + w2 * expf(acc2.y) + w3 * expf(acc3.y);
    float tot2 = w0 * expf(acc0.z) + w1 * expf(acc1.z) + w2 * expf(acc2.z) + w3 * expf(acc3.z);
    float tot3 = w0 * expf(acc0.w) + w1 * expf(acc1.w) + w2 * expf(acc2.w) + w3 * expf(acc3.w);

    #pragma unroll
    for (int m = 1; m < 16; m <<= 1) {
        tot0 += __shfl_xor(tot0, m);
        tot1 += __shfl_xor(tot1, m);
        tot2 += __shfl_xor(tot2, m);
        tot3 += __shfl_xor(tot3, m);
    }
    if (col == 0) {
        float* ob = out + (size_t)batch * ostride + (size_t)blockIdx.x * TM + wave * 16 + quad * 4;
        atomicAdd(ob + 0, tot0);
        atomicAdd(ob + 1, tot1);
        atomicAdd(ob + 2, tot2);
        atomicAdd(ob + 3, tot3);
    }
}

// ---------------------------------------------------------------------------
// Kernel 3: per-token numerator score  zs[tok] . W_en[x_en[tok]]  (exact fp32)
// ---------------------------------------------------------------------------
__global__ void en_score_kernel(const float* __restrict__ zs,
                                const float* __restrict__ W_en,
                                const int* __restrict__ x_en,
                                float* __restrict__ en_score)
{
    int tok  = blockIdx.x * 4 + (threadIdx.x >> 6);
    int lane = threadIdx.x & 63;
    int idx  = x_en[tok];
    float4 z = *(const float4*)(zs   + (size_t)tok * DDIM + lane * 4);
    float4 w = *(const float4*)(W_en + (size_t)idx * DDIM + lane * 4);
    float s = z.x * w.x + z.y * w.y + z.z * w.z + z.w * w.w;
    #pragma unroll
    for (int m = 32; m; m >>= 1) s += __shfl_xor(s, m);
    if (lane == 0) en_score[tok] = s;
}

__global__ void inv_kernel(const float* __restrict__ denom_fr,
                           float* __restrict__ invd)
{
    int i = blockIdx.x * 256 + threadIdx.x;
    if (i < NTOK) invd[i] = 1.0f / denom_fr[i];
}

// ---------------------------------------------------------------------------
// Kernel 4: final losses. One 64-lane wave per batch b.
// en: sum_s (score - log denom_en) * en_mask ; fr: sum_f log(t_fr) * fr_mask
// ---------------------------------------------------------------------------
__global__ void loss_kernel(const float* __restrict__ en_score,
                            const float* __restrict__ denom_en,
                            const float* __restrict__ t_fr,
                            const float* __restrict__ en_mask,
                            const float* __restrict__ fr_mask,
                            float* __restrict__ out)
{
    int b = blockIdx.x;
    int s = threadIdx.x;       // 64 threads = 1 wave
    int i = b * 64 + s;
    float a = (en_score[i] - logf(denom_en[i])) * en_mask[i];
    float c = logf(t_fr[i]) * fr_mask[i];
    #pragma unroll
    for (int m = 32; m; m >>= 1) { a += __shfl_xor(a, m); c += __shfl_xor(c, m); }
    if (s == 0) { out[b] = a; out[64 + b] = c; }
}

extern "C" void kernel_launch(void* const* d_in, const int* in_sizes, int n_in,
                              void* d_out, int out_size, void* d_ws, size_t ws_size,
                              hipStream_t stream)
{
    const float* zs       = (const float*)d_in[0];
    const int*   x_en     = (const int*)d_in[1];
    const int*   x_fr     = (const int*)d_in[2];
    const float* en_mask  = (const float*)d_in[3];
    const float* fr_mask  = (const float*)d_in[4];
    const float* W_en     = (const float*)d_in[5];
    const float* W_fr     = (const float*)d_in[6];
    const int*   pos_en   = (const int*)d_in[7];
    const int*   neg_en   = (const int*)d_in[8];
    const int*   pos_fr   = (const int*)d_in[9];
    const int*   neg_fr   = (const int*)d_in[10];
    const float* kappa_en = (const float*)d_in[11];
    const float* kappa_fr = (const float*)d_in[12];

    int Pe  = in_sizes[7];
    int Pf  = in_sizes[9];
    int Lpe = (Pe + NEGN + 63) & ~63;
    int Lpf = (Pf + NEGN + 63) & ~63;

    char* w = (char*)d_ws;
    float* denom_en = (float*)w; w += NTOK * 4;
    float* denom_fr = (float*)w; w += NTOK * 4;
    float* t_fr     = (float*)w; w += NTOK * 4;
    float* invd     = (float*)w; w += NTOK * 4;
    float* en_score = (float*)w; w += NTOK * 4;
    float* w_en     = (float*)w; w += (size_t)Lpe * 4;
    float* w_fr     = (float*)w; w += (size_t)Lpf * 4;
    unsigned short* z_bf  = (unsigned short*)w; w += (size_t)NTOK * DDIM * 2;
    unsigned short* E_en  = (unsigned short*)w; w += (size_t)Lpe * DDIM * 2;
    unsigned short* E_fr  = (unsigned short*)w; w += (size_t)Lpf * DDIM * 2;
    unsigned short* be_fr = (unsigned short*)w; w += (size_t)NTOK * DDIM * 2;

    // zero the accumulators (denom_en, denom_fr, t_fr are contiguous)
    hipMemsetAsync(denom_en, 0, (size_t)NTOK * 3 * 4, stream);

    int totrows = NTOK + Lpe + Lpf + NTOK;
    gather_kernel<<<(totrows + 3) / 4, 256, 0, stream>>>(
        zs, W_en, W_fr, pos_en, neg_en, pos_fr, neg_fr, x_fr,
        kappa_en, kappa_fr, z_bf, E_en, E_fr, be_fr, w_en, w_fr,
        Pe, Pf, Lpe, Lpf);

    // denominators: [4096 x Lp] weighted exp-sum GEMMs
    expsum_gemm<<<dim3(NTOK / TM, Lpe / TN, 1), 256, 0, stream>>>(
        z_bf, E_en, w_en, denom_en, 0, 0, 0, 0);
    expsum_gemm<<<dim3(NTOK / TM, Lpf / TN, 1), 256, 0, stream>>>(
        z_bf, E_fr, w_fr, denom_fr, 0, 0, 0, 0);

    inv_kernel<<<NTOK / 256, 256, 0, stream>>>(denom_fr, invd);

    // fr alignment: per-b 64x64 exp-sum GEMM weighted by 1/denom_fr[b,s]
    expsum_gemm<<<dim3(1, 1, 64), 256, 0, stream>>>(
        be_fr, z_bf, invd, t_fr, 64 * DDIM, 64 * DDIM, 64, 64);

    en_score_kernel<<<NTOK / 4, 256, 0, stream>>>(zs, W_en, x_en, en_score);

    loss_kernel<<<64, 64, 0, stream>>>(en_score, denom_en, t_fr,
                                       en_mask, fr_mask, (float*)d_out);
}

// Round 2
// 240.207 us; speedup vs baseline: 1.1531x; 1.1531x over previous
//
#include <hip/hip_runtime.h>

#define DDIM 256
#define NTOK 4096   // B*S = 64*64
#define NEGN 8192
#define BTM 128     // big-gemm tile M
#define BTN 128     // big-gemm tile N
// small 64x64 kernel (fr alignment)
#define TM 64
#define TN 64
#define LDT 40      // padded halfs per LDS row for the small kernel

typedef __attribute__((ext_vector_type(8))) short bf16x8;
typedef __attribute__((ext_vector_type(4))) float f32x4;

__device__ inline unsigned short f2bf(float f) {
    unsigned int u = __float_as_uint(f);
    unsigned int r = u + 0x7FFFu + ((u >> 16) & 1u);
    return (unsigned short)(r >> 16);
}

// CK-style global->LDS direct load, 16B per lane. LDS dest is wave-uniform
// base + lane*16 (m104/m108 caveat), so layout must be contiguous per issue.
__device__ inline void gl_lds16(const unsigned short* g, unsigned short* l) {
    __builtin_amdgcn_global_load_lds(
        reinterpret_cast<__attribute__((address_space(1))) unsigned int*>(
            reinterpret_cast<uintptr_t>(g)),
        reinterpret_cast<__attribute__((address_space(3))) unsigned int*>(
            reinterpret_cast<uintptr_t>(l)),
        16, 0, 0);
}

// ---------------------------------------------------------------------------
// Kernel 1: gather + fp32->bf16 convert (unchanged structure; E is one buffer)
// ---------------------------------------------------------------------------
__global__ void gather_kernel(
    const float* __restrict__ zs,
    const float* __restrict__ W_en, const float* __restrict__ W_fr,
    const int* __restrict__ pos_en, const int* __restrict__ neg_en,
    const int* __restrict__ pos_fr, const int* __restrict__ neg_fr,
    const int* __restrict__ x_fr,
    const float* __restrict__ kappa_en, const float* __restrict__ kappa_fr,
    unsigned short* __restrict__ z_bf,
    unsigned short* __restrict__ E_en, unsigned short* __restrict__ E_fr,
    unsigned short* __restrict__ be_fr,
    float* __restrict__ w_en, float* __restrict__ w_fr,
    int Pe, int Pf, int Lpe, int Lpf)
{
    int row  = blockIdx.x * 4 + (threadIdx.x >> 6);
    int lane = threadIdx.x & 63;
    const float* src = nullptr;
    unsigned short* dst = nullptr;
    bool zero = false;

    if (row < NTOK) {
        src = zs + (size_t)row * DDIM;
        dst = z_bf + (size_t)row * DDIM;
    } else if (row < NTOK + Lpe) {
        int j = row - NTOK;
        int Le = Pe + NEGN;
        int idx = 0;
        if (j < Pe)      idx = pos_en[j];
        else if (j < Le) idx = neg_en[j - Pe];
        else             zero = true;
        src = W_en + (size_t)idx * DDIM;
        dst = E_en + (size_t)j * DDIM;
        if (lane == 0) w_en[j] = (j < Pe) ? 1.0f : (j < Le ? kappa_en[0] : 0.0f);
    } else if (row < NTOK + Lpe + Lpf) {
        int j = row - NTOK - Lpe;
        int Lf = Pf + NEGN;
        int idx = 0;
        if (j < Pf)      idx = pos_fr[j];
        else if (j < Lf) idx = neg_fr[j - Pf];
        else             zero = true;
        src = W_fr + (size_t)idx * DDIM;
        dst = E_fr + (size_t)j * DDIM;
        if (lane == 0) w_fr[j] = (j < Pf) ? 1.0f : (j < Lf ? kappa_fr[0] : 0.0f);
    } else if (row < NTOK + Lpe + Lpf + NTOK) {
        int j = row - NTOK - Lpe - Lpf;
        int idx = x_fr[j];
        src = W_fr + (size_t)idx * DDIM;
        dst = be_fr + (size_t)j * DDIM;
    } else {
        return;
    }

    int d = lane * 4;
    float4 v;
    if (zero) { v.x = v.y = v.z = v.w = 0.0f; }
    else      { v = *(const float4*)(src + d); }
    ushort4 o;
    o.x = f2bf(v.x); o.y = f2bf(v.y); o.z = f2bf(v.z); o.w = f2bf(v.w);
    *(ushort4*)(dst + d) = o;
}

// ---------------------------------------------------------------------------
// Kernel 2: fused denominators. 128x128 tile, 4 waves in 2x2, 4x4 MFMA accs
// per wave, global_load_lds width-16 staging (m97 structure). B columns
// [0,ysplit) tiles -> denom_en, rest -> denom_fr.
// mfma_f32_16x16x32_bf16 layouts (verified round 1, absmax 0.0):
//   A/B frag: lane holds row (lane&15), 8 k-halfs at (lane>>4)*8
//   C/D:      n-col = lane&15, m-row = (lane>>4)*4 + reg
// ---------------------------------------------------------------------------
__global__ __launch_bounds__(256) void expsum_gemm128(
    const unsigned short* __restrict__ A,   // [4096 x 256] bf16 (z)
    const unsigned short* __restrict__ E,   // [(Lpe+Lpf) x 256] bf16
    const float* __restrict__ wts,          // [Lpe+Lpf]
    float* __restrict__ out_en, float* __restrict__ out_fr,
    int ysplit, int Lpe)
{
    __shared__ __align__(16) unsigned short As[BTM * 32];
    __shared__ __align__(16) unsigned short Bs[BTN * 32];

    int t    = threadIdx.x;
    int lane = t & 63;
    int wave = t >> 6;
    int col  = lane & 15;
    int quad = lane >> 4;
    int wm   = wave & 1;
    int wn   = wave >> 1;

    int yb = blockIdx.y;
    const unsigned short* Bb;
    float* out;
    int nbase;
    if (yb < ysplit) {
        Bb = E + (size_t)yb * BTN * DDIM;
        out = out_en; nbase = yb * BTN;
    } else {
        Bb = E + ((size_t)Lpe + (size_t)(yb - ysplit) * BTN) * DDIM;
        out = out_fr; nbase = Lpe + (yb - ysplit) * BTN;
    }
    const unsigned short* Ab = A + (size_t)blockIdx.x * BTM * DDIM;

    // staging: wave w, issue q in {0,1} covers 16 rows [32w+16q, +16)
    int srow = 32 * wave + (lane >> 2);   // q=0 row
    int koff = (lane & 3) * 8;            // halfs
    unsigned short* lA0 = As + (32 * wave) * 32;
    unsigned short* lA1 = As + (32 * wave + 16) * 32;
    unsigned short* lB0 = Bs + (32 * wave) * 32;
    unsigned short* lB1 = Bs + (32 * wave + 16) * 32;

    f32x4 acc[4][4];
    #pragma unroll
    for (int i = 0; i < 4; i++)
        #pragma unroll
        for (int j = 0; j < 4; j++)
            acc[i][j] = (f32x4){0.f, 0.f, 0.f, 0.f};

    for (int kk = 0; kk < DDIM; kk += 32) {
        __syncthreads();   // previous iter's LDS reads complete
        gl_lds16(Ab + (size_t)srow        * DDIM + kk + koff, lA0);
        gl_lds16(Ab + (size_t)(srow + 16) * DDIM + kk + koff, lA1);
        gl_lds16(Bb + (size_t)srow        * DDIM + kk + koff, lB0);
        gl_lds16(Bb + (size_t)(srow + 16) * DDIM + kk + koff, lB1);
        __syncthreads();   // vmcnt(0) drain -> tiles resident

        bf16x8 af[4], bfv[4];
        #pragma unroll
        for (int i = 0; i < 4; i++)
            af[i] = *(const bf16x8*)(As + (wm * 64 + 16 * i + col) * 32 + quad * 8);
        #pragma unroll
        for (int j = 0; j < 4; j++)
            bfv[j] = *(const bf16x8*)(Bs + (wn * 64 + 16 * j + col) * 32 + quad * 8);
        #pragma unroll
        for (int i = 0; i < 4; i++)
            #pragma unroll
            for (int j = 0; j < 4; j++)
                acc[i][j] = __builtin_amdgcn_mfma_f32_16x16x32_bf16(af[i], bfv[j], acc[i][j], 0, 0, 0);
    }

    // epilogue: weighted exp, reduce over the 128 n-cols of this tile
    float wj[4];
    #pragma unroll
    for (int j = 0; j < 4; j++)
        wj[j] = wts[nbase + wn * 64 + 16 * j + col];

    #pragma unroll
    for (int i = 0; i < 4; i++) {
        #pragma unroll
        for (int r = 0; r < 4; r++) {
            float s = wj[0] * __expf(acc[i][0][r]) + wj[1] * __expf(acc[i][1][r])
                    + wj[2] * __expf(acc[i][2][r]) + wj[3] * __expf(acc[i][3][r]);
            s += __shfl_xor(s, 1);
            s += __shfl_xor(s, 2);
            s += __shfl_xor(s, 4);
            s += __shfl_xor(s, 8);
            if (col == 0)
                atomicAdd(out + blockIdx.x * BTM + wm * 64 + 16 * i + quad * 4 + r, s);
        }
    }
}

// ---------------------------------------------------------------------------
// Kernel 3: fr alignment, per-batch 64x64 exp-sum with reciprocal weights
// (weight n = 1/denom_fr[b,n]); single block per batch -> direct store.
// ---------------------------------------------------------------------------
__global__ __launch_bounds__(256) void expsum_gemm64(
    const unsigned short* __restrict__ A,   // be_fr [B][64 x 256]
    const unsigned short* __restrict__ Bm,  // z_bf  [B][64 x 256]
    const float* __restrict__ denom,        // denom_fr [B*64]
    float* __restrict__ out)                // t_fr [B*64]
{
    __shared__ __align__(16) unsigned short lda[TM * LDT];
    __shared__ __align__(16) unsigned short ldb[TN * LDT];

    int batch = blockIdx.x;
    const unsigned short* Ab = A  + (size_t)batch * TM * DDIM;
    const unsigned short* Bb = Bm + (size_t)batch * TN * DDIM;

    int t      = threadIdx.x;
    int srow   = t >> 2;
    int schunk = t & 3;
    int lane   = t & 63;
    int wave   = t >> 6;
    int col    = lane & 15;
    int quad   = lane >> 4;

    f32x4 acc0 = {0.f,0.f,0.f,0.f};
    f32x4 acc1 = {0.f,0.f,0.f,0.f};
    f32x4 acc2 = {0.f,0.f,0.f,0.f};
    f32x4 acc3 = {0.f,0.f,0.f,0.f};

    for (int kk = 0; kk < DDIM; kk += 32) {
        uint4 av = *(const uint4*)(Ab + (size_t)srow * DDIM + kk + schunk * 8);
        uint4 bv = *(const uint4*)(Bb + (size_t)srow * DDIM + kk + schunk * 8);
        __syncthreads();
        *(uint4*)(lda + srow * LDT + schunk * 8) = av;
        *(uint4*)(ldb + srow * LDT + schunk * 8) = bv;
        __syncthreads();

        bf16x8 af = *(const bf16x8*)(lda + (wave * 16 + col) * LDT + quad * 8);
        bf16x8 b0 = *(const bf16x8*)(ldb + ( 0 + col) * LDT + quad * 8);
        bf16x8 b1 = *(const bf16x8*)(ldb + (16 + col) * LDT + quad * 8);
        bf16x8 b2 = *(const bf16x8*)(ldb + (32 + col) * LDT + quad * 8);
        bf16x8 b3 = *(const bf16x8*)(ldb + (48 + col) * LDT + quad * 8);
        acc0 = __builtin_amdgcn_mfma_f32_16x16x32_bf16(af, b0, acc0, 0, 0, 0);
        acc1 = __builtin_amdgcn_mfma_f32_16x16x32_bf16(af, b1, acc1, 0, 0, 0);
        acc2 = __builtin_amdgcn_mfma_f32_16x16x32_bf16(af, b2, acc2, 0, 0, 0);
        acc3 = __builtin_amdgcn_mfma_f32_16x16x32_bf16(af, b3, acc3, 0, 0, 0);
    }

    const float* db = denom + batch * 64;
    float w0 = 1.0f / db[ 0 + col];
    float w1 = 1.0f / db[16 + col];
    float w2 = 1.0f / db[32 + col];
    float w3 = 1.0f / db[48 + col];

    float tot0 = w0 * __expf(acc0.x) + w1 * __expf(acc1.x) + w2 * __expf(acc2.x) + w3 * __expf(acc3.x);
    float tot1 = w0 * __expf(acc0.y) + w1 * __expf(acc1.y) + w2 * __expf(acc2.y) + w3 * __expf(acc3.y);
    float tot2 = w0 * __expf(acc0.z) + w1 * __expf(acc1.z) + w2 * __expf(acc2.z) + w3 * __expf(acc3.z);
    float tot3 = w0 * __expf(acc0.w) + w1 * __expf(acc1.w) + w2 * __expf(acc2.w) + w3 * __expf(acc3.w);

    #pragma unroll
    for (int m = 1; m < 16; m <<= 1) {
        tot0 += __shfl_xor(tot0, m);
        tot1 += __shfl_xor(tot1, m);
        tot2 += __shfl_xor(tot2, m);
        tot3 += __shfl_xor(tot3, m);
    }
    if (col == 0) {
        float* ob = out + batch * 64 + wave * 16 + quad * 4;
        ob[0] = tot0; ob[1] = tot1; ob[2] = tot2; ob[3] = tot3;
    }
}

// ---------------------------------------------------------------------------
// Kernel 4: per-token numerator score  zs[tok] . W_en[x_en[tok]]  (exact fp32)
// ---------------------------------------------------------------------------
__global__ void en_score_kernel(const float* __restrict__ zs,
                                const float* __restrict__ W_en,
                                const int* __restrict__ x_en,
                                float* __restrict__ en_score)
{
    int tok  = blockIdx.x * 4 + (threadIdx.x >> 6);
    int lane = threadIdx.x & 63;
    int idx  = x_en[tok];
    float4 z = *(const float4*)(zs   + (size_t)tok * DDIM + lane * 4);
    float4 w = *(const float4*)(W_en + (size_t)idx * DDIM + lane * 4);
    float s = z.x * w.x + z.y * w.y + z.z * w.z + z.w * w.w;
    #pragma unroll
    for (int m = 32; m; m >>= 1) s += __shfl_xor(s, m);
    if (lane == 0) en_score[tok] = s;
}

// ---------------------------------------------------------------------------
// Kernel 5: final losses. One 64-lane wave per batch b.
// ---------------------------------------------------------------------------
__global__ void loss_kernel(const float* __restrict__ en_score,
                            const float* __restrict__ denom_en,
                            const float* __restrict__ t_fr,
                            const float* __restrict__ en_mask,
                            const float* __restrict__ fr_mask,
                            float* __restrict__ out)
{
    int b = blockIdx.x;
    int s = threadIdx.x;       // 64 threads = 1 wave
    int i = b * 64 + s;
    float a = (en_score[i] - __logf(denom_en[i])) * en_mask[i];
    float c = __logf(t_fr[i]) * fr_mask[i];
    #pragma unroll
    for (int m = 32; m; m >>= 1) { a += __shfl_xor(a, m); c += __shfl_xor(c, m); }
    if (s == 0) { out[b] = a; out[64 + b] = c; }
}

extern "C" void kernel_launch(void* const* d_in, const int* in_sizes, int n_in,
                              void* d_out, int out_size, void* d_ws, size_t ws_size,
                              hipStream_t stream)
{
    const float* zs       = (const float*)d_in[0];
    const int*   x_en     = (const int*)d_in[1];
    const int*   x_fr     = (const int*)d_in[2];
    const float* en_mask  = (const float*)d_in[3];
    const float* fr_mask  = (const float*)d_in[4];
    const float* W_en     = (const float*)d_in[5];
    const float* W_fr     = (const float*)d_in[6];
    const int*   pos_en   = (const int*)d_in[7];
    const int*   neg_en   = (const int*)d_in[8];
    const int*   pos_fr   = (const int*)d_in[9];
    const int*   neg_fr   = (const int*)d_in[10];
    const float* kappa_en = (const float*)d_in[11];
    const float* kappa_fr = (const float*)d_in[12];

    int Pe  = in_sizes[7];
    int Pf  = in_sizes[9];
    int Lpe = (Pe + NEGN + 127) & ~127;   // 128-aligned for BTN tiles
    int Lpf = (Pf + NEGN + 127) & ~127;

    char* w = (char*)d_ws;
    float* denom_en = (float*)w; w += NTOK * 4;
    float* denom_fr = (float*)w; w += NTOK * 4;
    float* t_fr     = (float*)w; w += NTOK * 4;
    float* en_score = (float*)w; w += NTOK * 4;
    float* w_all    = (float*)w; w += (size_t)(Lpe + Lpf) * 4;
    unsigned short* z_bf  = (unsigned short*)w; w += (size_t)NTOK * DDIM * 2;
    unsigned short* E_all = (unsigned short*)w; w += (size_t)(Lpe + Lpf) * DDIM * 2;
    unsigned short* be_fr = (unsigned short*)w; w += (size_t)NTOK * DDIM * 2;

    // zero the atomic accumulators (denom_en, denom_fr adjacent)
    hipMemsetAsync(denom_en, 0, (size_t)NTOK * 2 * 4, stream);

    int totrows = NTOK + Lpe + Lpf + NTOK;
    gather_kernel<<<(totrows + 3) / 4, 256, 0, stream>>>(
        zs, W_en, W_fr, pos_en, neg_en, pos_fr, neg_fr, x_fr,
        kappa_en, kappa_fr, z_bf, E_all, E_all + (size_t)Lpe * DDIM, be_fr,
        w_all, w_all + Lpe, Pe, Pf, Lpe, Lpf);

    // fused denominators: one dispatch, y tiles split en|fr
    int NE = Lpe / BTN, NF = Lpf / BTN;
    expsum_gemm128<<<dim3(NTOK / BTM, NE + NF, 1), 256, 0, stream>>>(
        z_bf, E_all, w_all, denom_en, denom_fr, NE, Lpe);

    en_score_kernel<<<NTOK / 4, 256, 0, stream>>>(zs, W_en, x_en, en_score);

    // fr alignment: per-b 64x64 exp-sum weighted by 1/denom_fr (fused recip)
    expsum_gemm64<<<64, 256, 0, stream>>>(be_fr, z_bf, denom_fr, t_fr);

    loss_kernel<<<64, 64, 0, stream>>>(en_score, denom_en, t_fr,
                                       en_mask, fr_mask, (float*)d_out);
}